// Round 2
// baseline (512.371 us; speedup 1.0000x reference)
//
#include <hip/hip_runtime.h>
#include <hip/hip_bf16.h>
#include <math.h>
#include <stdint.h>

#define B_BATCH   1024
#define D_DIM     512
#define C_CLASSES 100000
#define BM        256
#define BN        256
#define BK        64
#define KT        (D_DIM / BK)                     // 8 K-tiles
#define MT4       (B_BATCH / BM)                   // 4
#define NT256     ((C_CLASSES + BN - 1) / BN)      // 391
#define GRID_G    (MT4 * NT256)                    // 1564 blocks, exact
#define LOG2E     1.44269504088896340736f
#define COSM      0.87758256189037276f             // cos(0.5)
#define SINM      0.47942553860420301f             // sin(0.5)
#define NEG_LOG_EPS 69.07755278982137f             // -ln(1e-30)

typedef short bf16x8 __attribute__((ext_vector_type(8)));
typedef float f32x4  __attribute__((ext_vector_type(4)));

#define FENCE asm volatile("" ::: "memory")
#define BAR() do { FENCE; __builtin_amdgcn_s_barrier(); FENCE; } while (0)
#define VMW0() asm volatile("s_waitcnt vmcnt(0)" ::: "memory")

static __device__ __forceinline__ unsigned short f2bf(float f) {
    unsigned int u = __builtin_bit_cast(unsigned int, f);
    u += 0x7fffu + ((u >> 16) & 1u);              // round-to-nearest-even
    return (unsigned short)(u >> 16);
}

static __device__ __forceinline__ unsigned int pk_bf16_trunc(float lo, float hi) {
    return __builtin_amdgcn_perm(__builtin_bit_cast(unsigned int, hi),
                                 __builtin_bit_cast(unsigned int, lo),
                                 0x07060302u);
}

// async 16B/lane global -> LDS (LDS dest = wave-uniform base + lane*16)
static __device__ __forceinline__ void gld16(const unsigned short* g, unsigned short* l) {
    __builtin_amdgcn_global_load_lds(
        (const __attribute__((address_space(1))) unsigned int*)g,
        (__attribute__((address_space(3))) unsigned int*)l, 16, 0, 0);
}

// ---------------- kernel 1: normalize embeddings -> bf16 A [1024 x 512] ---
__global__ __launch_bounds__(256) void norm_embed(const float* __restrict__ E,
                                                  unsigned short* __restrict__ Abf) {
    const int b = blockIdx.x;
    const int t = threadIdx.x;
    float2 v = ((const float2*)(E + (size_t)b * D_DIM))[t];
    float ss = v.x * v.x + v.y * v.y;
    #pragma unroll
    for (int off = 1; off < 64; off <<= 1) ss += __shfl_xor(ss, off);
    __shared__ float ws4[4];
    if ((t & 63) == 0) ws4[t >> 6] = ss;
    __syncthreads();
    float inv = rsqrtf(ws4[0] + ws4[1] + ws4[2] + ws4[3]);
    unsigned int packed = (unsigned int)f2bf(v.x * inv) |
                          ((unsigned int)f2bf(v.y * inv) << 16);
    ((unsigned int*)Abf)[(size_t)b * (D_DIM / 2) + t] = packed;
}

// ---------------- kernel 1b: normalize weights -> bf16 [C x 512] ----------
__global__ __launch_bounds__(256) void norm_weight(const float* __restrict__ W,
                                                   unsigned short* __restrict__ Wbf) {
    const int wave = threadIdx.x >> 6;
    const int lane = threadIdx.x & 63;
    const int row0 = blockIdx.x * 8 + wave * 2;
    const int row1 = row0 + 1;
    const float4* s0 = (const float4*)(W + (size_t)row0 * D_DIM);
    const float4* s1 = (const float4*)(W + (size_t)row1 * D_DIM);
    float4 a0 = s0[lane];
    float4 a1 = s0[lane + 64];
    float4 b0 = s1[lane];
    float4 b1 = s1[lane + 64];
    float sa = a0.x*a0.x + a0.y*a0.y + a0.z*a0.z + a0.w*a0.w
             + a1.x*a1.x + a1.y*a1.y + a1.z*a1.z + a1.w*a1.w;
    float sb = b0.x*b0.x + b0.y*b0.y + b0.z*b0.z + b0.w*b0.w
             + b1.x*b1.x + b1.y*b1.y + b1.z*b1.z + b1.w*b1.w;
    #pragma unroll
    for (int off = 1; off < 64; off <<= 1) {
        sa += __shfl_xor(sa, off);
        sb += __shfl_xor(sb, off);
    }
    float ia = rsqrtf(sa), ib = rsqrtf(sb);
    uint2* d0 = (uint2*)(Wbf + (size_t)row0 * D_DIM);
    uint2* d1 = (uint2*)(Wbf + (size_t)row1 * D_DIM);
    uint2 oa0 = {pk_bf16_trunc(a0.x*ia, a0.y*ia), pk_bf16_trunc(a0.z*ia, a0.w*ia)};
    uint2 oa1 = {pk_bf16_trunc(a1.x*ia, a1.y*ia), pk_bf16_trunc(a1.z*ia, a1.w*ia)};
    uint2 ob0 = {pk_bf16_trunc(b0.x*ib, b0.y*ib), pk_bf16_trunc(b0.z*ib, b0.w*ib)};
    uint2 ob1 = {pk_bf16_trunc(b1.x*ib, b1.y*ib), pk_bf16_trunc(b1.z*ib, b1.w*ib)};
    d0[lane] = oa0; d0[lane + 64] = oa1;
    d1[lane] = ob0; d1[lane + 64] = ob1;
}

// epilogue per-element: clip, ArcFace margin (identity form), returns exp(s-64)
static __device__ __forceinline__ float epi_term(float accv, int col, int lab,
                                                 float* __restrict__ st, int srow) {
    float c = fminf(1.f, fmaxf(-1.f, accv));
    if (col >= C_CLASSES) return 0.f;
    float s = c * 64.0f;
    if (col == lab) {
        float sn = sqrtf(fmaxf(0.f, 1.f - c * c));
        float nm = c * COSM - sn * SINM;          // cos(theta + m)
        if (c < -COSM) nm = -1.f;                 // theta + m > pi
        s = nm * 64.0f;
        st[srow] = s;                             // unique writer across grid
    }
    return exp2f((s - 64.0f) * LOG2E);
}

// ---------------- kernel 2: 256x256 8-phase bf16 GEMM + margin + softmax ---
// T1 (bijective XCD chunk) + T2 (XOR-16B-slot swizzle, inverse-swizzled
// global source per rule #21) + T3/T4 (phase-split, staging issued 2.5
// phases ahead of the single boundary wait) + T5 (setprio around MFMA).
// 8 waves (2M x 4N), per-wave C = 128x64 = acc[8][4] f32x4.
// LDS: A,B double-buffered 64 KiB each + rowSum/labs = 130 KiB -> 1 block/CU.
__global__ __launch_bounds__(512, 2) void gemm_cos(const unsigned short* __restrict__ Abf,
                                                   const unsigned short* __restrict__ Wbf,
                                                   const int* __restrict__ labels,
                                                   float* __restrict__ st,
                                                   float* __restrict__ partial) {
    __shared__ __align__(16) unsigned short sA[2 * 256 * 64];  // 64 KiB
    __shared__ __align__(16) unsigned short sB[2 * 256 * 64];  // 64 KiB
    __shared__ float rowSum[BM];
    __shared__ int   labs[BM];

    // bijective XCD-chunk swizzle (m204): q=195, r=4; m-fastest within chunk
    const int orig = blockIdx.x;
    const int xcd  = orig & 7;
    const int pos  = orig >> 3;
    const int qq   = GRID_G >> 3;                 // 195
    const int rr   = GRID_G & 7;                  // 4
    const int wg   = (xcd < rr ? xcd * (qq + 1) : rr * (qq + 1) + (xcd - rr) * qq) + pos;
    const int mt = wg & 3;
    const int nt = wg >> 2;
    const int m0 = mt * BM;
    const int n0 = nt * BN;

    const int tid  = threadIdx.x;
    const int lane = tid & 63;
    const int wave = tid >> 6;
    const int wm = wave & 1;            // M half (rows wm*128 .. +127)
    const int wn = wave >> 1;           // N quarter (cols wn*64 .. +63)
    const int l15 = lane & 15, quad = lane >> 4;

    if (tid < BM) { labs[tid] = labels[m0 + tid]; rowSum[tid] = 0.f; }

    // ---- staging lane constants (inverse-swizzled global source) ----
    // LDS linear slot for this lane: row = i*64 + wave*8 + (lane>>3),
    // col16 = lane&7.  Content must be global col16 = (lane&7) ^ (row&7)
    // = (lane&7) ^ (lane>>3), so the swizzled READ returns logical data.
    const int srow  = wave * 8 + (lane >> 3);
    const int scolb = (((lane & 7) ^ (lane >> 3)) << 4);
    const char* gA[2][2];
    const char* gB[2][2];
    #pragma unroll
    for (int h = 0; h < 2; ++h)
        #pragma unroll
        for (int i = 0; i < 2; ++i) {
            gA[h][i] = (const char*)Abf + (size_t)(m0 + h * 128 + i * 64 + srow) * (D_DIM * 2) + scolb;
            int rB = min(n0 + h * 128 + i * 64 + srow, C_CLASSES - 1);
            gB[h][i] = (const char*)Wbf + (size_t)rB * (D_DIM * 2) + scolb;
        }

    // ---- prologue: stage K-tile 0 into buffer 0 ----
    {
        unsigned short* dA = sA + wave * 512;
        unsigned short* dB = sB + wave * 512;
        #pragma unroll
        for (int h = 0; h < 2; ++h)
            #pragma unroll
            for (int i = 0; i < 2; ++i) {
                gld16((const unsigned short*)gA[h][i], dA + h * 8192 + i * 4096);
                gA[h][i] += 128;
                gld16((const unsigned short*)gB[h][i], dB + h * 8192 + i * 4096);
                gB[h][i] += 128;
            }
    }

    const f32x4 z = (f32x4){0.f, 0.f, 0.f, 0.f};
    f32x4 acc[8][4];
    #pragma unroll
    for (int m = 0; m < 8; ++m)
        #pragma unroll
        for (int n = 0; n < 4; ++n) acc[m][n] = z;

    bf16x8 af[4][2];                    // current 4 mreps x 2 k-halves
    bf16x8 bfr[4][2];                   // all 4 nreps x 2 k-halves

    // swizzled read: byte off within row = (slot16 ^ (row&7)) * 16;
    // row&7 == l15&7 for all frag rows -> fold into qsw.
    const int qsw = ((quad ^ (l15 & 7)) << 4);

    for (int t = 0; t < KT; ++t) {
        const int p  = t & 1;
        const int pn = p ^ 1;

        // ---- tile boundary: own staging of tile t landed; barrier makes
        // every wave's staging visible. (Loads were issued 2.5 phases ago.)
        VMW0();
        BAR();

        const char* pa = (const char*)sA + (size_t)p * 32768 + (size_t)(wm * 128 + l15) * 128;
        const char* pb = (const char*)sB + (size_t)p * 32768 + (size_t)(wn * 64  + l15) * 128;

        // ================= phase 0: reads A(m0-3)+B(n0-1), stage A(t+1) ====
        #pragma unroll
        for (int m = 0; m < 4; ++m)
            #pragma unroll
            for (int kh = 0; kh < 2; ++kh)
                af[m][kh] = *(const bf16x8*)(pa + m * 2048 + (qsw ^ (kh << 6)));
        #pragma unroll
        for (int n = 0; n < 2; ++n)
            #pragma unroll
            for (int kh = 0; kh < 2; ++kh)
                bfr[n][kh] = *(const bf16x8*)(pb + n * 2048 + (qsw ^ (kh << 6)));
        if (t < KT - 1) {
            unsigned short* dA = sA + pn * 16384 + wave * 512;
            #pragma unroll
            for (int h = 0; h < 2; ++h)
                #pragma unroll
                for (int i = 0; i < 2; ++i) {
                    gld16((const unsigned short*)gA[h][i], dA + h * 8192 + i * 4096);
                    gA[h][i] += 128;
                }
        }
        BAR();
        __builtin_amdgcn_s_setprio(1);
        #pragma unroll
        for (int m = 0; m < 4; ++m)
            #pragma unroll
            for (int n = 0; n < 2; ++n)
                #pragma unroll
                for (int kh = 0; kh < 2; ++kh)
                    acc[m][n] = __builtin_amdgcn_mfma_f32_16x16x32_bf16(af[m][kh], bfr[n][kh], acc[m][n], 0, 0, 0);
        __builtin_amdgcn_s_setprio(0);
        BAR();

        // ================= phase 1: reads B(n2-3), stage B(t+1) ============
        #pragma unroll
        for (int n = 2; n < 4; ++n)
            #pragma unroll
            for (int kh = 0; kh < 2; ++kh)
                bfr[n][kh] = *(const bf16x8*)(pb + n * 2048 + (qsw ^ (kh << 6)));
        if (t < KT - 1) {
            unsigned short* dB = sB + pn * 16384 + wave * 512;
            #pragma unroll
            for (int h = 0; h < 2; ++h)
                #pragma unroll
                for (int i = 0; i < 2; ++i) {
                    gld16((const unsigned short*)gB[h][i], dB + h * 8192 + i * 4096);
                    gB[h][i] += 128;
                }
        }
        BAR();
        __builtin_amdgcn_s_setprio(1);
        #pragma unroll
        for (int m = 0; m < 4; ++m)
            #pragma unroll
            for (int n = 2; n < 4; ++n)
                #pragma unroll
                for (int kh = 0; kh < 2; ++kh)
                    acc[m][n] = __builtin_amdgcn_mfma_f32_16x16x32_bf16(af[m][kh], bfr[n][kh], acc[m][n], 0, 0, 0);
        __builtin_amdgcn_s_setprio(0);
        BAR();

        // ================= phase 2: reads A(m4-7) ==========================
        #pragma unroll
        for (int m = 0; m < 4; ++m)
            #pragma unroll
            for (int kh = 0; kh < 2; ++kh)
                af[m][kh] = *(const bf16x8*)(pa + 8192 + m * 2048 + (qsw ^ (kh << 6)));
        BAR();
        __builtin_amdgcn_s_setprio(1);
        #pragma unroll
        for (int m = 0; m < 4; ++m)
            #pragma unroll
            for (int n = 2; n < 4; ++n)
                #pragma unroll
                for (int kh = 0; kh < 2; ++kh)
                    acc[4 + m][n] = __builtin_amdgcn_mfma_f32_16x16x32_bf16(af[m][kh], bfr[n][kh], acc[4 + m][n], 0, 0, 0);
        __builtin_amdgcn_s_setprio(0);
        BAR();

        // ================= phase 3: MFMA only (m4-7 x n0-1) ================
        __builtin_amdgcn_s_setprio(1);
        #pragma unroll
        for (int m = 0; m < 4; ++m)
            #pragma unroll
            for (int n = 0; n < 2; ++n)
                #pragma unroll
                for (int kh = 0; kh < 2; ++kh)
                    acc[4 + m][n] = __builtin_amdgcn_mfma_f32_16x16x32_bf16(af[m][kh], bfr[n][kh], acc[4 + m][n], 0, 0, 0);
        __builtin_amdgcn_s_setprio(0);
        // no trailing barrier: next loop-top VMW0+BAR is the boundary
    }

    // ---------------- epilogue ----------------
    const int colbase = n0 + wn * 64 + l15;
    #pragma unroll
    for (int m = 0; m < 8; ++m) {
        #pragma unroll
        for (int r = 0; r < 4; ++r) {
            const int rloc = wm * 128 + m * 16 + quad * 4 + r;
            const int lab = labs[rloc];
            float part = 0.f;
            #pragma unroll
            for (int n = 0; n < 4; ++n)
                part += epi_term(acc[m][n][r], colbase + n * 16, lab, st, m0 + rloc);
            part += __shfl_xor(part, 1);
            part += __shfl_xor(part, 2);
            part += __shfl_xor(part, 4);
            part += __shfl_xor(part, 8);
            if (l15 == 0) atomicAdd(&rowSum[rloc], part);
        }
    }

    __syncthreads();
    if (tid < BM) partial[(size_t)(m0 + tid) * NT256 + nt] = rowSum[tid];
}

// ---------------- kernel 3: per-row combine + mean loss ----------------
__global__ __launch_bounds__(64) void reduce_loss(const float* __restrict__ partial,
                                                  const float* __restrict__ st,
                                                  float* __restrict__ out) {
    const int b = blockIdx.x;
    const int l = threadIdx.x;
    const float* row = partial + (size_t)b * NT256;
    float L = 0.f;
    for (int t = l; t < NT256; t += 64) L += row[t];   // coalesced across lanes
    #pragma unroll
    for (int off = 1; off < 64; off <<= 1) L += __shfl_xor(L, off);
    if (l == 0) {
        float logp = st[b] - 64.0f - logf(L);
        float lossb = fminf(-logp, NEG_LOG_EPS) * (1.0f / (float)B_BATCH);
        atomicAdd(out, lossb);
    }
}

extern "C" void kernel_launch(void* const* d_in, const int* in_sizes, int n_in,
                              void* d_out, int out_size, void* d_ws, size_t ws_size,
                              hipStream_t stream) {
    const float* emb = (const float*)d_in[0];
    const float* wgt = (const float*)d_in[1];
    const int*   lab = (const int*)d_in[2];
    float* out = (float*)d_out;
    char* ws = (char*)d_ws;

    const size_t WBF_B = (size_t)C_CLASSES * D_DIM * 2;  // 102,400,000
    const size_t ABF_B = (size_t)B_BATCH * D_DIM * 2;    // 1,048,576

    unsigned short* Wbf = (unsigned short*)ws;
    unsigned short* Abf = (unsigned short*)(ws + WBF_B);
    float* st      = (float*)(ws + WBF_B + ABF_B);
    float* partial = (float*)(ws + WBF_B + ABF_B + 4096);

    hipMemsetAsync(d_out, 0, sizeof(float), stream);
    norm_embed<<<B_BATCH, 256, 0, stream>>>(emb, Abf);
    norm_weight<<<C_CLASSES / 8, 256, 0, stream>>>(wgt, Wbf);
    gemm_cos<<<GRID_G, 512, 0, stream>>>(Abf, Wbf, lab, st, partial);
    reduce_loss<<<B_BATCH, 64, 0, stream>>>(partial, st, out);
}

// Round 3
// 468.854 us; speedup vs baseline: 1.0928x; 1.0928x over previous
//
#include <hip/hip_runtime.h>
#include <hip/hip_bf16.h>
#include <math.h>
#include <stdint.h>

#define B_BATCH   1024
#define D_DIM     512
#define C_CLASSES 100000
#define BM        128
#define BN        128
#define BK        32
#define KITERS    (D_DIM / BK)                    // 16
#define MTILES    (B_BATCH / BM)                  // 8
#define NTILES    ((C_CLASSES + BN - 1) / BN)     // 782
#define NGROUPS   98                              // ceil(782/8)
#define GRID_G    (8 * 8 * NGROUPS)               // 6272 blocks (16 early-exit)
#define LOG2E     1.44269504088896340736f
#define COSM      0.87758256189037276f            // cos(0.5)
#define SINM      0.47942553860420301f            // sin(0.5)
#define NEG_LOG_EPS 69.07755278982137f            // -ln(1e-30)

typedef short bf16x8 __attribute__((ext_vector_type(8)));
typedef float f32x4  __attribute__((ext_vector_type(4)));

static __device__ __forceinline__ unsigned short f2bf(float f) {
    unsigned int u = __builtin_bit_cast(unsigned int, f);
    u += 0x7fffu + ((u >> 16) & 1u);              // round-to-nearest-even
    return (unsigned short)(u >> 16);
}

static __device__ __forceinline__ unsigned int pk_bf16_trunc(float lo, float hi) {
    return __builtin_amdgcn_perm(__builtin_bit_cast(unsigned int, hi),
                                 __builtin_bit_cast(unsigned int, lo),
                                 0x07060302u);
}

// async 16B/lane global -> LDS (LDS dest = wave-uniform base + lane*16)
static __device__ __forceinline__ void gld16(const unsigned short* g, unsigned short* l) {
    __builtin_amdgcn_global_load_lds(
        (const __attribute__((address_space(1))) unsigned int*)g,
        (__attribute__((address_space(3))) unsigned int*)l, 16, 0, 0);
}

// ---------------- kernel 1: normalize embeddings -> bf16 A [1024 x 512] ---
__global__ __launch_bounds__(256) void norm_embed(const float* __restrict__ E,
                                                  unsigned short* __restrict__ Abf) {
    const int b = blockIdx.x;
    const int t = threadIdx.x;
    float2 v = ((const float2*)(E + (size_t)b * D_DIM))[t];
    float ss = v.x * v.x + v.y * v.y;
    #pragma unroll
    for (int off = 1; off < 64; off <<= 1) ss += __shfl_xor(ss, off);
    __shared__ float ws4[4];
    if ((t & 63) == 0) ws4[t >> 6] = ss;
    __syncthreads();
    float inv = rsqrtf(ws4[0] + ws4[1] + ws4[2] + ws4[3]);
    unsigned int packed = (unsigned int)f2bf(v.x * inv) |
                          ((unsigned int)f2bf(v.y * inv) << 16);
    ((unsigned int*)Abf)[(size_t)b * (D_DIM / 2) + t] = packed;
}

// ---------------- kernel 1b: normalize weights -> bf16 [C x 512] ----------
__global__ __launch_bounds__(256) void norm_weight(const float* __restrict__ W,
                                                   unsigned short* __restrict__ Wbf) {
    const int wave = threadIdx.x >> 6;
    const int lane = threadIdx.x & 63;
    const int row0 = blockIdx.x * 8 + wave * 2;
    const int row1 = row0 + 1;
    const float4* s0 = (const float4*)(W + (size_t)row0 * D_DIM);
    const float4* s1 = (const float4*)(W + (size_t)row1 * D_DIM);
    float4 a0 = s0[lane];
    float4 a1 = s0[lane + 64];
    float4 b0 = s1[lane];
    float4 b1 = s1[lane + 64];
    float sa = a0.x*a0.x + a0.y*a0.y + a0.z*a0.z + a0.w*a0.w
             + a1.x*a1.x + a1.y*a1.y + a1.z*a1.z + a1.w*a1.w;
    float sb = b0.x*b0.x + b0.y*b0.y + b0.z*b0.z + b0.w*b0.w
             + b1.x*b1.x + b1.y*b1.y + b1.z*b1.z + b1.w*b1.w;
    #pragma unroll
    for (int off = 1; off < 64; off <<= 1) {
        sa += __shfl_xor(sa, off);
        sb += __shfl_xor(sb, off);
    }
    float ia = rsqrtf(sa), ib = rsqrtf(sb);
    uint2* d0 = (uint2*)(Wbf + (size_t)row0 * D_DIM);
    uint2* d1 = (uint2*)(Wbf + (size_t)row1 * D_DIM);
    uint2 oa0 = {pk_bf16_trunc(a0.x*ia, a0.y*ia), pk_bf16_trunc(a0.z*ia, a0.w*ia)};
    uint2 oa1 = {pk_bf16_trunc(a1.x*ia, a1.y*ia), pk_bf16_trunc(a1.z*ia, a1.w*ia)};
    uint2 ob0 = {pk_bf16_trunc(b0.x*ib, b0.y*ib), pk_bf16_trunc(b0.z*ib, b0.w*ib)};
    uint2 ob1 = {pk_bf16_trunc(b1.x*ib, b1.y*ib), pk_bf16_trunc(b1.z*ib, b1.w*ib)};
    d0[lane] = oa0; d0[lane + 64] = oa1;
    d1[lane] = ob0; d1[lane + 64] = ob1;
}

// epilogue per-element: clip, ArcFace margin (identity form), returns exp(s-64)
static __device__ __forceinline__ float epi_term(float accv, int col, int lab,
                                                 float* __restrict__ st, int srow) {
    float c = fminf(1.f, fmaxf(-1.f, accv));
    if (col >= C_CLASSES) return 0.f;
    float s = c * 64.0f;
    if (col == lab) {
        float sn = sqrtf(fmaxf(0.f, 1.f - c * c));
        float nm = c * COSM - sn * SINM;          // cos(theta + m)
        if (c < -COSM) nm = -1.f;                 // theta + m > pi
        s = nm * 64.0f;
        st[srow] = s;                             // unique writer across grid
    }
    return exp2f((s - 64.0f) * LOG2E);
}

// ---------------- kernel 2: bf16 GEMM + margin + partial softmax ----------
// Round-1 structure (measured 174 us @ (256,4)) + T3 minimum-2-phase reorder:
// LDS double-buffered (33 KiB -> still 4 blocks/CU), next-tile staging issued
// FIRST, then ds_read+MFMA of current tile, ONE __syncthreads per K-step
// (its implicit vmcnt(0) lands a full iteration after the gld16 issue,
// instead of zero instructions after as in round-1's 2-barrier loop).
// Tripwires: VGPR<=128 (4 blocks/CU), WRITE_SIZE ~26MB, absmax 0.
__global__ __launch_bounds__(256, 4) void gemm_cos(const unsigned short* __restrict__ Abf,
                                                   const unsigned short* __restrict__ Wbf,
                                                   const int* __restrict__ labels,
                                                   float* __restrict__ st,
                                                   float* __restrict__ partial) {
    __shared__ unsigned short As[2][BM * BK];   // 2 x 8 KiB (global_load_lds layout)
    __shared__ unsigned short Bs[2][BN * BK];   // 2 x 8 KiB
    __shared__ float rowSum[BM];
    __shared__ int   labs[BM];

    const int id = blockIdx.x;
    const int x  = id & 7;          // XCD slot
    const int s  = id >> 3;         // sequence on this XCD
    const int mt = s & 7;           // m-tile
    const int y  = x + 8 * (s >> 3);// n-tile: 8 consecutive s share y per XCD
    if (y >= NTILES) return;
    const int m0 = mt * BM;
    const int n0 = y * BN;

    const int tid = threadIdx.x;
    if (tid < BM) { labs[tid] = labels[m0 + tid]; rowSum[tid] = 0.f; }

    const int lane = tid & 63;
    const int wave = tid >> 6;
    const int wm = wave & 1, wn = wave >> 1;
    const int l15 = lane & 15, quad = lane >> 4;

    // staging: wave w stages chunks (2w),(2w+1); chunk c = tile rows [16c,16c+16)
    const int rsub = lane >> 2;
    const int cg   = (lane & 3) * 8;
    const int c0 = wave * 2, c1 = wave * 2 + 1;
    const unsigned short* gA0 = Abf + (size_t)(m0 + c0 * 16 + rsub) * D_DIM + cg;
    const unsigned short* gA1 = Abf + (size_t)(m0 + c1 * 16 + rsub) * D_DIM + cg;
    const int bR0 = min(n0 + c0 * 16 + rsub, C_CLASSES - 1);
    const int bR1 = min(n0 + c1 * 16 + rsub, C_CLASSES - 1);
    const unsigned short* gB0 = Wbf + (size_t)bR0 * D_DIM + cg;
    const unsigned short* gB1 = Wbf + (size_t)bR1 * D_DIM + cg;
    const int lo0 = c0 * 512, lo1 = c1 * 512;

    // prologue: stage K-tile 0 into buffer 0
    gld16(gA0, &As[0][lo0]); gld16(gA1, &As[0][lo1]);
    gld16(gB0, &Bs[0][lo0]); gld16(gB1, &Bs[0][lo1]);
    gA0 += BK; gA1 += BK; gB0 += BK; gB1 += BK;

    const f32x4 z = (f32x4){0.f, 0.f, 0.f, 0.f};
    f32x4 a00 = z, a01 = z, a02 = z, a03 = z;
    f32x4 a10 = z, a11 = z, a12 = z, a13 = z;
    f32x4 a20 = z, a21 = z, a22 = z, a23 = z;
    f32x4 a30 = z, a31 = z, a32 = z, a33 = z;

    const int aro = (wm * 64 + l15) * BK + quad * 8;
    const int bro = (wn * 64 + l15) * BK + quad * 8;

    for (int kk = 0; kk < KITERS; ++kk) {
        // implicit s_waitcnt vmcnt(0) lgkmcnt(0) + s_barrier: waits the stage
        // of tile kk (issued one full iteration ago) and retires all reads of
        // the buffer about to be overwritten.
        __syncthreads();
        const int cur = kk & 1;

        if (kk < KITERS - 1) {
            const int nxt = cur ^ 1;
            gld16(gA0, &As[nxt][lo0]); gld16(gA1, &As[nxt][lo1]);
            gld16(gB0, &Bs[nxt][lo0]); gld16(gB1, &Bs[nxt][lo1]);
            gA0 += BK; gA1 += BK; gB0 += BK; gB1 += BK;
        }

        bf16x8 af0 = *(const bf16x8*)&As[cur][aro];
        bf16x8 af1 = *(const bf16x8*)&As[cur][aro + 16 * BK];
        bf16x8 af2 = *(const bf16x8*)&As[cur][aro + 32 * BK];
        bf16x8 af3 = *(const bf16x8*)&As[cur][aro + 48 * BK];
        bf16x8 bf0 = *(const bf16x8*)&Bs[cur][bro];
        bf16x8 bf1 = *(const bf16x8*)&Bs[cur][bro + 16 * BK];
        bf16x8 bf2 = *(const bf16x8*)&Bs[cur][bro + 32 * BK];
        bf16x8 bf3 = *(const bf16x8*)&Bs[cur][bro + 48 * BK];

        a00 = __builtin_amdgcn_mfma_f32_16x16x32_bf16(af0, bf0, a00, 0, 0, 0);
        a01 = __builtin_amdgcn_mfma_f32_16x16x32_bf16(af0, bf1, a01, 0, 0, 0);
        a02 = __builtin_amdgcn_mfma_f32_16x16x32_bf16(af0, bf2, a02, 0, 0, 0);
        a03 = __builtin_amdgcn_mfma_f32_16x16x32_bf16(af0, bf3, a03, 0, 0, 0);
        a10 = __builtin_amdgcn_mfma_f32_16x16x32_bf16(af1, bf0, a10, 0, 0, 0);
        a11 = __builtin_amdgcn_mfma_f32_16x16x32_bf16(af1, bf1, a11, 0, 0, 0);
        a12 = __builtin_amdgcn_mfma_f32_16x16x32_bf16(af1, bf2, a12, 0, 0, 0);
        a13 = __builtin_amdgcn_mfma_f32_16x16x32_bf16(af1, bf3, a13, 0, 0, 0);
        a20 = __builtin_amdgcn_mfma_f32_16x16x32_bf16(af2, bf0, a20, 0, 0, 0);
        a21 = __builtin_amdgcn_mfma_f32_16x16x32_bf16(af2, bf1, a21, 0, 0, 0);
        a22 = __builtin_amdgcn_mfma_f32_16x16x32_bf16(af2, bf2, a22, 0, 0, 0);
        a23 = __builtin_amdgcn_mfma_f32_16x16x32_bf16(af2, bf3, a23, 0, 0, 0);
        a30 = __builtin_amdgcn_mfma_f32_16x16x32_bf16(af3, bf0, a30, 0, 0, 0);
        a31 = __builtin_amdgcn_mfma_f32_16x16x32_bf16(af3, bf1, a31, 0, 0, 0);
        a32 = __builtin_amdgcn_mfma_f32_16x16x32_bf16(af3, bf2, a32, 0, 0, 0);
        a33 = __builtin_amdgcn_mfma_f32_16x16x32_bf16(af3, bf3, a33, 0, 0, 0);
    }

    const int colbase = n0 + wn * 64 + l15;

    #define EPIROW(A0, A1, A2, A3, MI)                                         \
    {                                                                          \
        _Pragma("unroll")                                                      \
        for (int r = 0; r < 4; ++r) {                                          \
            const int rloc = wm * 64 + (MI) * 16 + quad * 4 + r;               \
            const int lab = labs[rloc];                                        \
            float part = 0.f;                                                  \
            part += epi_term((A0)[r], colbase,      lab, st, m0 + rloc);       \
            part += epi_term((A1)[r], colbase + 16, lab, st, m0 + rloc);       \
            part += epi_term((A2)[r], colbase + 32, lab, st, m0 + rloc);       \
            part += epi_term((A3)[r], colbase + 48, lab, st, m0 + rloc);       \
            part += __shfl_xor(part, 1);                                       \
            part += __shfl_xor(part, 2);                                       \
            part += __shfl_xor(part, 4);                                       \
            part += __shfl_xor(part, 8);                                       \
            if (l15 == 0) atomicAdd(&rowSum[rloc], part);                      \
        }                                                                      \
    }

    EPIROW(a00, a01, a02, a03, 0)
    EPIROW(a10, a11, a12, a13, 1)
    EPIROW(a20, a21, a22, a23, 2)
    EPIROW(a30, a31, a32, a33, 3)
    #undef EPIROW

    __syncthreads();
    // [B][NTILES] layout: reduce_loss reads are lane-contiguous (coalesced).
    if (tid < BM) partial[(size_t)(m0 + tid) * NTILES + y] = rowSum[tid];
}

// ---------------- kernel 3: per-row combine + mean loss ----------------
__global__ __launch_bounds__(64) void reduce_loss(const float* __restrict__ partial,
                                                  const float* __restrict__ st,
                                                  float* __restrict__ out) {
    const int b = blockIdx.x;
    const int l = threadIdx.x;
    const float* row = partial + (size_t)b * NTILES;
    float L = 0.f;
    for (int t = l; t < NTILES; t += 64) L += row[t];   // coalesced across lanes
    #pragma unroll
    for (int off = 1; off < 64; off <<= 1) L += __shfl_xor(L, off);
    if (l == 0) {
        float logp = st[b] - 64.0f - logf(L);
        float lossb = fminf(-logp, NEG_LOG_EPS) * (1.0f / (float)B_BATCH);
        atomicAdd(out, lossb);
    }
}

extern "C" void kernel_launch(void* const* d_in, const int* in_sizes, int n_in,
                              void* d_out, int out_size, void* d_ws, size_t ws_size,
                              hipStream_t stream) {
    const float* emb = (const float*)d_in[0];
    const float* wgt = (const float*)d_in[1];
    const int*   lab = (const int*)d_in[2];
    float* out = (float*)d_out;
    char* ws = (char*)d_ws;

    const size_t WBF_B = (size_t)C_CLASSES * D_DIM * 2;  // 102,400,000
    const size_t ABF_B = (size_t)B_BATCH * D_DIM * 2;    // 1,048,576

    unsigned short* Wbf = (unsigned short*)ws;
    unsigned short* Abf = (unsigned short*)(ws + WBF_B);
    float* st      = (float*)(ws + WBF_B + ABF_B);
    float* partial = (float*)(ws + WBF_B + ABF_B + 4096);

    hipMemsetAsync(d_out, 0, sizeof(float), stream);
    norm_embed<<<B_BATCH, 256, 0, stream>>>(emb, Abf);
    norm_weight<<<C_CLASSES / 8, 256, 0, stream>>>(wgt, Wbf);
    gemm_cos<<<GRID_G, 256, 0, stream>>>(Abf, Wbf, lab, st, partial);
    reduce_loss<<<B_BATCH, 64, 0, stream>>>(partial, st, out);
}

// Round 4
// 452.353 us; speedup vs baseline: 1.1327x; 1.0365x over previous
//
#include <hip/hip_runtime.h>
#include <hip/hip_bf16.h>
#include <math.h>
#include <stdint.h>

#define B_BATCH   1024
#define D_DIM     512
#define C_CLASSES 100000
#define BM        128
#define BN        128
#define BK        32
#define KITERS    (D_DIM / BK)                    // 16
#define MTILES    (B_BATCH / BM)                  // 8
#define NTILES    ((C_CLASSES + BN - 1) / BN)     // 782
#define NGROUPS   98                              // ceil(782/8)
#define GRID_G    (8 * 8 * NGROUPS)               // 6272 blocks (16 early-exit)
#define WBLK      (C_CLASSES / 8)                 // 12500 weight blocks in prep
#define ABLK      (B_BATCH / 8)                   // 128 embed blocks in prep
#define LOG2E     1.44269504088896340736f
#define COSM      0.87758256189037276f            // cos(0.5)
#define SINM      0.47942553860420301f            // sin(0.5)
#define NEG_LOG_EPS 69.07755278982137f            // -ln(1e-30)

typedef short bf16x8 __attribute__((ext_vector_type(8)));
typedef float f32x4  __attribute__((ext_vector_type(4)));

static __device__ __forceinline__ unsigned short f2bf(float f) {
    unsigned int u = __builtin_bit_cast(unsigned int, f);
    u += 0x7fffu + ((u >> 16) & 1u);              // round-to-nearest-even
    return (unsigned short)(u >> 16);
}

static __device__ __forceinline__ unsigned int pk_rne(float lo, float hi) {
    return (unsigned int)f2bf(lo) | ((unsigned int)f2bf(hi) << 16);
}

static __device__ __forceinline__ unsigned int pk_bf16_trunc(float lo, float hi) {
    return __builtin_amdgcn_perm(__builtin_bit_cast(unsigned int, hi),
                                 __builtin_bit_cast(unsigned int, lo),
                                 0x07060302u);
}

// async 16B/lane global -> LDS (LDS dest = wave-uniform base + lane*16)
static __device__ __forceinline__ void gld16(const unsigned short* g, unsigned short* l) {
    __builtin_amdgcn_global_load_lds(
        (const __attribute__((address_space(1))) unsigned int*)g,
        (__attribute__((address_space(3))) unsigned int*)l, 16, 0, 0);
}

// ------------- kernel 1: fused normalize (W rows + E rows) -> bf16 --------
// blocks [0,WBLK): weight rows (trunc pack, as measured-passing before)
// blocks [WBLK, WBLK+ABLK): embedding rows (RNE pack, as before)
// block WBLK, thread 0 zeroes the output scalar (replaces hipMemsetAsync).
// Lane layout: 2 consecutive float4 per row -> one 16B bf16 store per row.
__global__ __launch_bounds__(256) void prep(const float* __restrict__ W,
                                            const float* __restrict__ E,
                                            unsigned short* __restrict__ Wbf,
                                            unsigned short* __restrict__ Abf,
                                            float* __restrict__ out) {
    const int blk  = blockIdx.x;
    const int wave = threadIdx.x >> 6;
    const int lane = threadIdx.x & 63;
    const bool isW = blk < WBLK;
    if (!isW && blk == WBLK && threadIdx.x == 0) *out = 0.f;

    const float* src = isW ? W : E;
    unsigned short* dst = isW ? Wbf : Abf;
    const int r0 = (isW ? blk : blk - WBLK) * 8 + wave * 2;
    const int r1 = r0 + 1;

    const float4* s0 = (const float4*)(src + (size_t)r0 * D_DIM);
    const float4* s1 = (const float4*)(src + (size_t)r1 * D_DIM);
    float4 a0 = s0[2 * lane], a1 = s0[2 * lane + 1];
    float4 b0 = s1[2 * lane], b1 = s1[2 * lane + 1];

    float sa = a0.x*a0.x + a0.y*a0.y + a0.z*a0.z + a0.w*a0.w
             + a1.x*a1.x + a1.y*a1.y + a1.z*a1.z + a1.w*a1.w;
    float sb = b0.x*b0.x + b0.y*b0.y + b0.z*b0.z + b0.w*b0.w
             + b1.x*b1.x + b1.y*b1.y + b1.z*b1.z + b1.w*b1.w;
    #pragma unroll
    for (int off = 1; off < 64; off <<= 1) {
        sa += __shfl_xor(sa, off);
        sb += __shfl_xor(sb, off);
    }
    float ia = rsqrtf(sa), ib = rsqrtf(sb);
    a0.x *= ia; a0.y *= ia; a0.z *= ia; a0.w *= ia;
    a1.x *= ia; a1.y *= ia; a1.z *= ia; a1.w *= ia;
    b0.x *= ib; b0.y *= ib; b0.z *= ib; b0.w *= ib;
    b1.x *= ib; b1.y *= ib; b1.z *= ib; b1.w *= ib;

    uint4 oa, ob;
    if (isW) {   // trunc pack (4 VALU / 8 elems) — identical numerics to prior rounds
        oa = (uint4){pk_bf16_trunc(a0.x, a0.y), pk_bf16_trunc(a0.z, a0.w),
                     pk_bf16_trunc(a1.x, a1.y), pk_bf16_trunc(a1.z, a1.w)};
        ob = (uint4){pk_bf16_trunc(b0.x, b0.y), pk_bf16_trunc(b0.z, b0.w),
                     pk_bf16_trunc(b1.x, b1.y), pk_bf16_trunc(b1.z, b1.w)};
    } else {     // RNE pack for embeddings — identical numerics to prior rounds
        oa = (uint4){pk_rne(a0.x, a0.y), pk_rne(a0.z, a0.w),
                     pk_rne(a1.x, a1.y), pk_rne(a1.z, a1.w)};
        ob = (uint4){pk_rne(b0.x, b0.y), pk_rne(b0.z, b0.w),
                     pk_rne(b1.x, b1.y), pk_rne(b1.z, b1.w)};
    }
    ((uint4*)(dst + (size_t)r0 * D_DIM))[lane] = oa;
    ((uint4*)(dst + (size_t)r1 * D_DIM))[lane] = ob;
}

// epilogue per-element: clip, ArcFace margin (identity form), returns exp(s-64)
static __device__ __forceinline__ float epi_term(float accv, int col, int lab,
                                                 float* __restrict__ st, int srow) {
    float c = fminf(1.f, fmaxf(-1.f, accv));
    if (col >= C_CLASSES) return 0.f;
    float s = c * 64.0f;
    if (col == lab) {
        float sn = sqrtf(fmaxf(0.f, 1.f - c * c));
        float nm = c * COSM - sn * SINM;          // cos(theta + m)
        if (c < -COSM) nm = -1.f;                 // theta + m > pi
        s = nm * 64.0f;
        st[srow] = s;                             // unique writer across grid
    }
    return exp2f((s - 64.0f) * LOG2E);
}

// ---------------- kernel 2: bf16 GEMM + margin + partial softmax ----------
// EXACT round-1 structure (best measured: 174 us @ (256,4)). Schedule surgery
// is measured-flat on this tile (2-barrier=174, 8ph-drain0=225, dbuf=178.5);
// do not touch the loop again without a structurally different plan.
__global__ __launch_bounds__(256, 4) void gemm_cos(const unsigned short* __restrict__ Abf,
                                                   const unsigned short* __restrict__ Wbf,
                                                   const int* __restrict__ labels,
                                                   float* __restrict__ st,
                                                   float* __restrict__ partial) {
    __shared__ unsigned short As[BM * BK];   // 8 KiB, unpadded (global_load_lds layout)
    __shared__ unsigned short Bs[BN * BK];   // 8 KiB
    __shared__ float rowSum[BM];
    __shared__ int   labs[BM];

    const int id = blockIdx.x;
    const int x  = id & 7;          // XCD slot
    const int s  = id >> 3;         // sequence on this XCD
    const int mt = s & 7;           // m-tile
    const int y  = x + 8 * (s >> 3);// n-tile: 8 consecutive s share y per XCD
    if (y >= NTILES) return;
    const int m0 = mt * BM;
    const int n0 = y * BN;

    const int tid = threadIdx.x;
    if (tid < BM) { labs[tid] = labels[m0 + tid]; rowSum[tid] = 0.f; }

    const int lane = tid & 63;
    const int wave = tid >> 6;
    const int wm = wave & 1, wn = wave >> 1;
    const int l15 = lane & 15, quad = lane >> 4;

    // staging: wave w stages chunks (2w),(2w+1); chunk c = tile rows [16c,16c+16)
    const int rsub = lane >> 2;
    const int cg   = (lane & 3) * 8;
    const int c0 = wave * 2, c1 = wave * 2 + 1;
    const unsigned short* gA0 = Abf + (size_t)(m0 + c0 * 16 + rsub) * D_DIM + cg;
    const unsigned short* gA1 = Abf + (size_t)(m0 + c1 * 16 + rsub) * D_DIM + cg;
    const int bR0 = min(n0 + c0 * 16 + rsub, C_CLASSES - 1);
    const int bR1 = min(n0 + c1 * 16 + rsub, C_CLASSES - 1);
    const unsigned short* gB0 = Wbf + (size_t)bR0 * D_DIM + cg;
    const unsigned short* gB1 = Wbf + (size_t)bR1 * D_DIM + cg;
    unsigned short* lA0 = &As[c0 * 512];
    unsigned short* lA1 = &As[c1 * 512];
    unsigned short* lB0 = &Bs[c0 * 512];
    unsigned short* lB1 = &Bs[c1 * 512];

    const f32x4 z = (f32x4){0.f, 0.f, 0.f, 0.f};
    f32x4 a00 = z, a01 = z, a02 = z, a03 = z;
    f32x4 a10 = z, a11 = z, a12 = z, a13 = z;
    f32x4 a20 = z, a21 = z, a22 = z, a23 = z;
    f32x4 a30 = z, a31 = z, a32 = z, a33 = z;

    const int aro = (wm * 64 + l15) * BK + quad * 8;
    const int bro = (wn * 64 + l15) * BK + quad * 8;

    for (int kk = 0; kk < KITERS; ++kk) {
        __syncthreads();                     // prior frag reads done
        gld16(gA0, lA0); gld16(gA1, lA1);
        gld16(gB0, lB0); gld16(gB1, lB1);
        gA0 += BK; gA1 += BK; gB0 += BK; gB1 += BK;
        __syncthreads();                     // loads visible

        bf16x8 af0 = *(const bf16x8*)&As[aro];
        bf16x8 af1 = *(const bf16x8*)&As[aro + 16 * BK];
        bf16x8 af2 = *(const bf16x8*)&As[aro + 32 * BK];
        bf16x8 af3 = *(const bf16x8*)&As[aro + 48 * BK];
        bf16x8 bf0 = *(const bf16x8*)&Bs[bro];
        bf16x8 bf1 = *(const bf16x8*)&Bs[bro + 16 * BK];
        bf16x8 bf2 = *(const bf16x8*)&Bs[bro + 32 * BK];
        bf16x8 bf3 = *(const bf16x8*)&Bs[bro + 48 * BK];

        a00 = __builtin_amdgcn_mfma_f32_16x16x32_bf16(af0, bf0, a00, 0, 0, 0);
        a01 = __builtin_amdgcn_mfma_f32_16x16x32_bf16(af0, bf1, a01, 0, 0, 0);
        a02 = __builtin_amdgcn_mfma_f32_16x16x32_bf16(af0, bf2, a02, 0, 0, 0);
        a03 = __builtin_amdgcn_mfma_f32_16x16x32_bf16(af0, bf3, a03, 0, 0, 0);
        a10 = __builtin_amdgcn_mfma_f32_16x16x32_bf16(af1, bf0, a10, 0, 0, 0);
        a11 = __builtin_amdgcn_mfma_f32_16x16x32_bf16(af1, bf1, a11, 0, 0, 0);
        a12 = __builtin_amdgcn_mfma_f32_16x16x32_bf16(af1, bf2, a12, 0, 0, 0);
        a13 = __builtin_amdgcn_mfma_f32_16x16x32_bf16(af1, bf3, a13, 0, 0, 0);
        a20 = __builtin_amdgcn_mfma_f32_16x16x32_bf16(af2, bf0, a20, 0, 0, 0);
        a21 = __builtin_amdgcn_mfma_f32_16x16x32_bf16(af2, bf1, a21, 0, 0, 0);
        a22 = __builtin_amdgcn_mfma_f32_16x16x32_bf16(af2, bf2, a22, 0, 0, 0);
        a23 = __builtin_amdgcn_mfma_f32_16x16x32_bf16(af2, bf3, a23, 0, 0, 0);
        a30 = __builtin_amdgcn_mfma_f32_16x16x32_bf16(af3, bf0, a30, 0, 0, 0);
        a31 = __builtin_amdgcn_mfma_f32_16x16x32_bf16(af3, bf1, a31, 0, 0, 0);
        a32 = __builtin_amdgcn_mfma_f32_16x16x32_bf16(af3, bf2, a32, 0, 0, 0);
        a33 = __builtin_amdgcn_mfma_f32_16x16x32_bf16(af3, bf3, a33, 0, 0, 0);
    }

    const int colbase = n0 + wn * 64 + l15;

    #define EPIROW(A0, A1, A2, A3, MI)                                         \
    {                                                                          \
        _Pragma("unroll")                                                      \
        for (int r = 0; r < 4; ++r) {                                          \
            const int rloc = wm * 64 + (MI) * 16 + quad * 4 + r;               \
            const int lab = labs[rloc];                                        \
            float part = 0.f;                                                  \
            part += epi_term((A0)[r], colbase,      lab, st, m0 + rloc);       \
            part += epi_term((A1)[r], colbase + 16, lab, st, m0 + rloc);       \
            part += epi_term((A2)[r], colbase + 32, lab, st, m0 + rloc);       \
            part += epi_term((A3)[r], colbase + 48, lab, st, m0 + rloc);       \
            part += __shfl_xor(part, 1);                                       \
            part += __shfl_xor(part, 2);                                       \
            part += __shfl_xor(part, 4);                                       \
            part += __shfl_xor(part, 8);                                       \
            if (l15 == 0) atomicAdd(&rowSum[rloc], part);                      \
        }                                                                      \
    }

    EPIROW(a00, a01, a02, a03, 0)
    EPIROW(a10, a11, a12, a13, 1)
    EPIROW(a20, a21, a22, a23, 2)
    EPIROW(a30, a31, a32, a33, 3)
    #undef EPIROW

    __syncthreads();
    // [B][NTILES] layout: reduce_loss reads are lane-contiguous (coalesced).
    if (tid < BM) partial[(size_t)(m0 + tid) * NTILES + y] = rowSum[tid];
}

// ---------------- kernel 3: per-row combine + mean loss ----------------
__global__ __launch_bounds__(64) void reduce_loss(const float* __restrict__ partial,
                                                  const float* __restrict__ st,
                                                  float* __restrict__ out) {
    const int b = blockIdx.x;
    const int l = threadIdx.x;
    const float* row = partial + (size_t)b * NTILES;
    float L = 0.f;
    for (int t = l; t < NTILES; t += 64) L += row[t];   // coalesced across lanes
    #pragma unroll
    for (int off = 1; off < 64; off <<= 1) L += __shfl_xor(L, off);
    if (l == 0) {
        float logp = st[b] - 64.0f - logf(L);
        float lossb = fminf(-logp, NEG_LOG_EPS) * (1.0f / (float)B_BATCH);
        atomicAdd(out, lossb);
    }
}

extern "C" void kernel_launch(void* const* d_in, const int* in_sizes, int n_in,
                              void* d_out, int out_size, void* d_ws, size_t ws_size,
                              hipStream_t stream) {
    const float* emb = (const float*)d_in[0];
    const float* wgt = (const float*)d_in[1];
    const int*   lab = (const int*)d_in[2];
    float* out = (float*)d_out;
    char* ws = (char*)d_ws;

    const size_t WBF_B = (size_t)C_CLASSES * D_DIM * 2;  // 102,400,000
    const size_t ABF_B = (size_t)B_BATCH * D_DIM * 2;    // 1,048,576

    unsigned short* Wbf = (unsigned short*)ws;
    unsigned short* Abf = (unsigned short*)(ws + WBF_B);
    float* st      = (float*)(ws + WBF_B + ABF_B);
    float* partial = (float*)(ws + WBF_B + ABF_B + 4096);

    // 3 dispatches (was 5: memset folded into prep, embed+weight fused)
    prep<<<WBLK + ABLK, 256, 0, stream>>>(wgt, emb, Wbf, Abf, out);
    gemm_cos<<<GRID_G, 256, 0, stream>>>(Abf, Wbf, lab, st, partial);
    reduce_loss<<<B_BATCH, 64, 0, stream>>>(partial, st, out);
}